// Round 3
// baseline (4547.414 us; speedup 1.0000x reference)
//
#include <hip/hip_runtime.h>
#include <hip/hip_bf16.h>
#include <stdint.h>

#define M_DIM 2048
#define N_DIM 25000
#define K_DIM 32000
#define N_PAD 25088            // 98 * 256
#define NT_K  500              // K_DIM / 64

typedef __attribute__((ext_vector_type(8))) short short8;
typedef __attribute__((ext_vector_type(4))) float f32x4;

typedef __attribute__((address_space(1))) const void* as1cv;
typedef __attribute__((address_space(3))) void* as3v;
#define GLDS16(g, l) __builtin_amdgcn_global_load_lds((as1cv)(g), (as3v)(l), 16, 0, 0)

// round-to-nearest-even fp32 -> bf16
__device__ inline unsigned short f2bf(float x) {
  union { float f; unsigned u; } c; c.f = x;
  unsigned u = c.u;
  return (unsigned short)((u + 0x7fffu + ((u >> 16) & 1u)) >> 16);
}

__device__ inline short8 pack8(float4 a, float4 b) {
  short8 s;
  s[0] = (short)f2bf(a.x); s[1] = (short)f2bf(a.y);
  s[2] = (short)f2bf(a.z); s[3] = (short)f2bf(a.w);
  s[4] = (short)f2bf(b.x); s[5] = (short)f2bf(b.y);
  s[6] = (short)f2bf(b.z); s[7] = (short)f2bf(b.w);
  return s;
}

// ---------------- convert kernels (fp32 -> bf16 in workspace) ----------------

__global__ __launch_bounds__(256) void conv_a_kernel(const float* __restrict__ in,
                                                     unsigned short* __restrict__ out) {
  const size_t n8 = (size_t)M_DIM * K_DIM / 8;
  const size_t stride = (size_t)gridDim.x * blockDim.x;
  for (size_t i = (size_t)blockIdx.x * blockDim.x + threadIdx.x; i < n8; i += stride) {
    const float4* p = (const float4*)(in + i * 8);
    float4 v0 = p[0], v1 = p[1];
    *(short8*)(out + i * 8) = pack8(v0, v1);
  }
}

__global__ __launch_bounds__(256) void conv_b_kernel(const float* __restrict__ in,
                                                     unsigned short* __restrict__ out) {
  const size_t n8 = (size_t)N_PAD * K_DIM / 8;
  const size_t stride = (size_t)gridDim.x * blockDim.x;
  const size_t k8 = K_DIM / 8;  // 4000
  for (size_t i = (size_t)blockIdx.x * blockDim.x + threadIdx.x; i < n8; i += stride) {
    const size_t row = i / k8;
    short8 s = {0, 0, 0, 0, 0, 0, 0, 0};
    if (row < N_DIM) {
      const float4* p = (const float4*)(in + i * 8);
      float4 v0 = p[0], v1 = p[1];
      s = pack8(v0, v1);
    }
    *(short8*)(out + i * 8) = s;
  }
}

// ---------------- 256x256 8-phase GEMM, deep prefetch (vmcnt(6)) ----------------
// LDS per buffer: A 256x64 bf16 as 32 subtiles (16 rows x 32 cols, 1024 B), then B.
// Swizzle within subtile: 16B-chunk c' = c ^ ((row>>1)&3), applied to the
// pre-swizzled GLOBAL source on stage and to the ds_read address (rule 21).
//
// Stage schedule (steady state, iteration = tiles t (buf0), t+1 (buf1)):
//   P1: A(t+1)h1   [buf1.A h1 last read prev-P7]     -- waited at end-P4 (vmcnt 6)
//   P3: B(t+2)h0   [buf0.B free after P2]
//   P4: B(t+2)h1 + A(t+2)h0  [buf0.A free after P3]
//   P5: A(t+2)h1                                      -- all waited at end-P8 (vmcnt 6)
//   P7: B(t+3)h0   [buf1.B free after P6]
//   P8: B(t+3)h1 + A(t+3)h0  [buf1.A free after P7]   -- waited next end-P4
// Every waited half has 3-5 phases of flight; vmcnt ledger: 14 outstanding at
// each VMC, drain oldest 8 (= the tile needed next), leave 6.

#define BARR  __builtin_amdgcn_s_barrier()
#define LGKM0 do { asm volatile("s_waitcnt lgkmcnt(0)" ::: "memory"); \
                   __builtin_amdgcn_sched_barrier(0); } while (0)
#define LGKM8 asm volatile("s_waitcnt lgkmcnt(8)" ::: "memory")
#define VMC6  asm volatile("s_waitcnt vmcnt(6)" ::: "memory")
#define VMC0  asm volatile("s_waitcnt vmcnt(0)" ::: "memory")
#define PRIO1 __builtin_amdgcn_s_setprio(1)
#define PRIO0 __builtin_amdgcn_s_setprio(0)

#define READ_AF(P, MH) { _Pragma("unroll") for (int m2_ = 0; m2_ < 4; ++m2_) { \
  _Pragma("unroll") for (int kk_ = 0; kk_ < 2; ++kk_) \
    af[m2_][kk_] = *(const short8*)(rdA##P + (((MH) * 4 + m2_) * 2 + kk_) * 512); } }

#define READ_BF(P, NH) { _Pragma("unroll") for (int n2_ = 0; n2_ < 2; ++n2_) { \
  _Pragma("unroll") for (int kk_ = 0; kk_ < 2; ++kk_) \
    bf[NH][n2_][kk_] = *(const short8*)(rdB##P + (((NH) * 2 + n2_) * 2 + kk_) * 512); } }

#define MFMA_Q(MH, NH) { _Pragma("unroll") for (int kk_ = 0; kk_ < 2; ++kk_) { \
  _Pragma("unroll") for (int m2_ = 0; m2_ < 4; ++m2_) { \
  _Pragma("unroll") for (int n2_ = 0; n2_ < 2; ++n2_) \
    acc[(MH)*4+m2_][(NH)*2+n2_] = __builtin_amdgcn_mfma_f32_16x16x32_bf16( \
        af[m2_][kk_], bf[NH][n2_][kk_], acc[(MH)*4+m2_][(NH)*2+n2_], 0, 0, 0); } } }

#define STAGE_A(P, KT, H) do { \
  const unsigned short* s_ = agp + (size_t)(H) * (128 * (size_t)K_DIM) + (size_t)(KT) * 64; \
  GLDS16(s_,      stA##P + (H) * 8192); \
  GLDS16(s_ + 32, stA##P + (H) * 8192 + 512); } while (0)

#define STAGE_B(P, KT, H) do { \
  const unsigned short* s_ = bgp + (size_t)(H) * (128 * (size_t)K_DIM) + (size_t)(KT) * 64; \
  GLDS16(s_,      stB##P + (H) * 8192); \
  GLDS16(s_ + 32, stB##P + (H) * 8192 + 512); } while (0)

__global__ __launch_bounds__(512, 2)
void gemm8_kernel(const unsigned short* __restrict__ A, const unsigned short* __restrict__ B,
                  float* __restrict__ C) {
  extern __shared__ __align__(16) unsigned short lds[];  // 131072 B
  unsigned short* const LA0 = lds;
  unsigned short* const LB0 = lds + 16384;
  unsigned short* const LA1 = lds + 32768;
  unsigned short* const LB1 = lds + 49152;

  const int bid = blockIdx.x;
  const int wg = (bid & 7) * 96 + (bid >> 3);   // bijective XCD chunking (768 % 8 == 0)
  const int tm = wg & 7;                        // M tile 0..7 (fastest: shares B panel)
  const int tn = wg >> 3;                       // N tile 0..95 (cols 0..24575)
  const int tid = threadIdx.x;
  const int lane = tid & 63;
  const int w = tid >> 6;        // wave 0..7
  const int wm = w >> 2;         // 2 waves in M (128 rows each)
  const int wn = w & 3;          // 4 waves in N (64 cols each)

  const int laneoff = (lane & 15) * 32 + (((lane >> 4) ^ ((lane >> 1) & 3)) << 3);
  const unsigned short* const rdA0 = LA0 + wm * (16 * 512) + laneoff;
  const unsigned short* const rdA1 = LA1 + wm * (16 * 512) + laneoff;
  const int bsub = (wn >> 1) * 16 + (wn & 1) * 8;
  const unsigned short* const rdB0 = LB0 + bsub * 512 + laneoff;
  const unsigned short* const rdB1 = LB1 + bsub * 512 + laneoff;

  const int srow = w * 16 + (lane >> 2);
  const int schunk = ((lane & 3) ^ ((lane >> 3) & 3)) * 8;
  const unsigned short* const agp = A + (size_t)(tm * 256 + srow) * K_DIM + schunk;
  const unsigned short* const bgp = B + (size_t)(tn * 256 + srow) * K_DIM + schunk;
  unsigned short* const stA0 = LA0 + w * 1024;
  unsigned short* const stA1 = LA1 + w * 1024;
  unsigned short* const stB0 = LB0 + w * 1024;
  unsigned short* const stB1 = LB1 + w * 1024;

  f32x4 acc[8][4];
  const f32x4 z4 = {0.f, 0.f, 0.f, 0.f};
  #pragma unroll
  for (int i = 0; i < 8; ++i)
    #pragma unroll
    for (int j = 0; j < 4; ++j) acc[i][j] = z4;

  short8 af[4][2];      // current mh: 4 m-frags x 2 k-slices
  short8 bf[2][2][2];   // [nh][n'][kk]

  // ---- prologue: tile0 (4 halves) + tile1 {Bh0, Bh1, Ah0}; drain tile0 ----
  STAGE_B(0, 0, 0); STAGE_B(0, 0, 1);
  STAGE_A(0, 0, 0); STAGE_A(0, 0, 1);
  STAGE_B(1, 1, 0); STAGE_B(1, 1, 1); STAGE_A(1, 1, 0);
  VMC6; BARR;

  // ---- main loop: tiles (t, t+1), t = 0,2,...,496 ----
  #pragma unroll 1
  for (int it = 0; it < 249; ++it) {
    const int t = 2 * it;
    // P1: reads for Q(0,0); stage A(t+1)h1 -> buf1
    READ_AF(0, 0); READ_BF(0, 0); STAGE_A(1, t + 1, 1);
    LGKM8; BARR; LGKM0; PRIO1; MFMA_Q(0, 0); PRIO0; BARR;
    // P2
    READ_BF(0, 1);
    BARR; LGKM0; PRIO1; MFMA_Q(0, 1); PRIO0; BARR;
    // P3: stage B(t+2)h0 -> buf0  [buf0.B free after P2]
    READ_AF(0, 1); STAGE_B(0, t + 2, 0);
    BARR; LGKM0; PRIO1; MFMA_Q(1, 1); PRIO0; BARR;
    // P4: stage B(t+2)h1 + A(t+2)h0 -> buf0  [buf0.A free after P3]; wait tile t+1
    STAGE_B(0, t + 2, 1); STAGE_A(0, t + 2, 0);
    BARR; PRIO1; MFMA_Q(1, 0); PRIO0; VMC6; BARR;
    // P5: stage A(t+2)h1 -> buf0
    READ_AF(1, 0); READ_BF(1, 0); STAGE_A(0, t + 2, 1);
    LGKM8; BARR; LGKM0; PRIO1; MFMA_Q(0, 0); PRIO0; BARR;
    // P6
    READ_BF(1, 1);
    BARR; LGKM0; PRIO1; MFMA_Q(0, 1); PRIO0; BARR;
    // P7: stage B(t+3)h0 -> buf1  [buf1.B free after P6]
    READ_AF(1, 1); STAGE_B(1, t + 3, 0);
    BARR; LGKM0; PRIO1; MFMA_Q(1, 1); PRIO0; BARR;
    // P8: stage B(t+3)h1 + A(t+3)h0 -> buf1  [buf1.A free after P7]; wait tile t+2
    STAGE_B(1, t + 3, 1); STAGE_A(1, t + 3, 0);
    BARR; PRIO1; MFMA_Q(1, 0); PRIO0; VMC6; BARR;
  }

  // ---- tail: tile 498 (buf0; stage A(499)h1), then tile 499 (buf1) ----
  READ_AF(0, 0); READ_BF(0, 0); STAGE_A(1, 499, 1);
  LGKM8; BARR; LGKM0; PRIO1; MFMA_Q(0, 0); PRIO0; BARR;
  READ_BF(0, 1);
  BARR; LGKM0; PRIO1; MFMA_Q(0, 1); PRIO0; BARR;
  READ_AF(0, 1);
  BARR; LGKM0; PRIO1; MFMA_Q(1, 1); PRIO0; BARR;
  BARR; PRIO1; MFMA_Q(1, 0); PRIO0; VMC0; BARR;
  READ_AF(1, 0); READ_BF(1, 0);
  LGKM8; BARR; LGKM0; PRIO1; MFMA_Q(0, 0); PRIO0; BARR;
  READ_BF(1, 1);
  BARR; LGKM0; PRIO1; MFMA_Q(0, 1); PRIO0; BARR;
  READ_AF(1, 1);
  BARR; LGKM0; PRIO1; MFMA_Q(1, 1); PRIO0; BARR;
  PRIO1; MFMA_Q(1, 0); PRIO0;

  // ---- epilogue: C/D layout col=lane&15, row=(lane>>4)*4+j [m89-verified] ----
  const int crow0 = tm * 256 + wm * 128 + (lane >> 4) * 4;
  const int ccol0 = tn * 256 + wn * 64 + (lane & 15);
  #pragma unroll
  for (int m = 0; m < 8; ++m) {
    #pragma unroll
    for (int n = 0; n < 4; ++n) {
      const int col = ccol0 + n * 16;
      float* cp = C + (size_t)(crow0 + m * 16) * N_DIM + col;
      #pragma unroll
      for (int j = 0; j < 4; ++j)
        cp[(size_t)j * N_DIM] = acc[m][n][j];
    }
  }
}

// ---------------- remainder kernel: cols 24576..25087 (r1-validated structure) ----------------

__device__ inline void mfma_tile_fb(const unsigned short* As, const unsigned short* Bs,
                                    f32x4 acc[4][4], int lane, int wr, int wc) {
  const int ar = lane & 15;
  const int ko = (lane >> 4) * 8;
  #pragma unroll
  for (int kk = 0; kk < 2; ++kk) {
    short8 a2[4], b2[4];
    #pragma unroll
    for (int m = 0; m < 4; ++m)
      a2[m] = *(const short8*)&As[(wr * 64 + m * 16 + ar) * 64 + kk * 32 + ko];
    #pragma unroll
    for (int n = 0; n < 4; ++n)
      b2[n] = *(const short8*)&Bs[(wc * 64 + n * 16 + ar) * 64 + kk * 32 + ko];
    #pragma unroll
    for (int m = 0; m < 4; ++m)
      #pragma unroll
      for (int n = 0; n < 4; ++n)
        acc[m][n] = __builtin_amdgcn_mfma_f32_16x16x32_bf16(a2[m], b2[n], acc[m][n], 0, 0, 0);
  }
}

__global__ __launch_bounds__(256, 2)
void gemm_rem_kernel(const unsigned short* __restrict__ A, const unsigned short* __restrict__ B,
                     float* __restrict__ C) {
  __shared__ __align__(16) unsigned short As[128 * 64];
  __shared__ __align__(16) unsigned short Bs[128 * 64];
  const int tm = blockIdx.x & 15;               // 16 M tiles of 128
  const int tn = 192 + (blockIdx.x >> 4);       // cols 24576..25087 (B ws zero-padded)
  const int tid = threadIdx.x;
  const int lane = tid & 63;
  const int w = tid >> 6;
  const int wr = w >> 1;
  const int wc = w & 1;
  f32x4 acc[4][4];
  const f32x4 z4 = {0.f, 0.f, 0.f, 0.f};
  #pragma unroll
  for (int i = 0; i < 4; ++i)
    #pragma unroll
    for (int j = 0; j < 4; ++j) acc[i][j] = z4;
  const int lrow = lane >> 3;
  const int lc16 = lane & 7;
  const unsigned short* ag = A + (size_t)(tm * 128 + w * 32 + lrow) * K_DIM + lc16 * 8;
  const unsigned short* bg = B + (size_t)(tn * 128 + w * 32 + lrow) * K_DIM + lc16 * 8;
  for (int kt = 0; kt < NT_K; ++kt) {
    #pragma unroll
    for (int i = 0; i < 4; ++i) {
      GLDS16(ag + (size_t)(i * 8) * K_DIM, &As[(w * 32 + i * 8) * 64]);
      GLDS16(bg + (size_t)(i * 8) * K_DIM, &Bs[(w * 32 + i * 8) * 64]);
    }
    ag += 64; bg += 64;
    __syncthreads();
    mfma_tile_fb(As, Bs, acc, lane, wr, wc);
    __syncthreads();
  }
  const int crow0 = tm * 128 + wr * 64 + (lane >> 4) * 4;
  const int ccol0 = tn * 128 + wc * 64 + (lane & 15);
  #pragma unroll
  for (int m = 0; m < 4; ++m) {
    #pragma unroll
    for (int n = 0; n < 4; ++n) {
      const int col = ccol0 + n * 16;
      if (col < N_DIM) {
        float* cp = C + (size_t)(crow0 + m * 16) * N_DIM + col;
        #pragma unroll
        for (int j = 0; j < 4; ++j)
          cp[(size_t)j * N_DIM] = acc[m][n][j];
      }
    }
  }
}

// ---------------- fallback (r1-validated 128^2 reg-staged fp32 path) ----------------

__global__ __launch_bounds__(256, 2)
void gemm_fb_kernel(const float* __restrict__ A, const float* __restrict__ B,
                    float* __restrict__ C) {
  __shared__ __align__(16) unsigned short As[128 * 64];
  __shared__ __align__(16) unsigned short Bs[128 * 64];
  const int bid = blockIdx.x;
  const int wg = (bid & 7) * (3136 / 8) + (bid >> 3);
  const int tm = wg % 16;
  const int tn = wg / 16;
  const int tid = threadIdx.x;
  const int lane = tid & 63;
  const int w = tid >> 6;
  const int wr = w >> 1;
  const int wc = w & 1;
  f32x4 acc[4][4];
  const f32x4 z4 = {0.f, 0.f, 0.f, 0.f};
  #pragma unroll
  for (int i = 0; i < 4; ++i)
    #pragma unroll
    for (int j = 0; j < 4; ++j) acc[i][j] = z4;
  for (int kt = 0; kt < NT_K; ++kt) {
    const int k0 = kt * 64;
    #pragma unroll
    for (int r = 0; r < 4; ++r) {
      const int f0 = r * 512 + tid * 2;
      const int row = f0 >> 4;
      const int c4 = f0 & 15;
      const float* ga = A + (size_t)(tm * 128 + row) * K_DIM + k0 + c4 * 4;
      float4 v0 = *(const float4*)ga;
      float4 v1 = *(const float4*)(ga + 4);
      *(short8*)&As[row * 64 + c4 * 4] = pack8(v0, v1);
    }
    #pragma unroll
    for (int r = 0; r < 4; ++r) {
      const int f0 = r * 512 + tid * 2;
      const int row = f0 >> 4;
      const int c4 = f0 & 15;
      const int grow = tn * 128 + row;
      short8 s = {0, 0, 0, 0, 0, 0, 0, 0};
      if (grow < N_DIM) {
        const float* gb = B + (size_t)grow * K_DIM + k0 + c4 * 4;
        float4 v0 = *(const float4*)gb;
        float4 v1 = *(const float4*)(gb + 4);
        s = pack8(v0, v1);
      }
      *(short8*)&Bs[row * 64 + c4 * 4] = s;
    }
    __syncthreads();
    mfma_tile_fb(As, Bs, acc, lane, wr, wc);
    __syncthreads();
  }
  const int crow0 = tm * 128 + wr * 64 + (lane >> 4) * 4;
  const int ccol0 = tn * 128 + wc * 64 + (lane & 15);
  #pragma unroll
  for (int m = 0; m < 4; ++m) {
    #pragma unroll
    for (int n = 0; n < 4; ++n) {
      const int col = ccol0 + n * 16;
      if (col < N_DIM) {
        float* cp = C + (size_t)(crow0 + m * 16) * N_DIM + col;
        #pragma unroll
        for (int j = 0; j < 4; ++j)
          cp[(size_t)j * N_DIM] = acc[m][n][j];
      }
    }
  }
}

// ---------------- launch ----------------

extern "C" void kernel_launch(void* const* d_in, const int* in_sizes, int n_in,
                              void* d_out, int out_size, void* d_ws, size_t ws_size,
                              hipStream_t stream) {
  const float* A = (const float*)d_in[0];   // teacher_logits [2048][32000] fp32
  const float* B = (const float*)d_in[1];   // projection   [25000][32000] fp32
  float* C = (float*)d_out;                 // [2048][25000] fp32

  const size_t needA = (size_t)M_DIM * K_DIM * 2;
  const size_t needB = (size_t)N_PAD * K_DIM * 2;

  if (ws_size >= needA + needB) {
    unsigned short* wsA = (unsigned short*)d_ws;
    unsigned short* wsB = wsA + (size_t)M_DIM * K_DIM;
    conv_a_kernel<<<2048, 256, 0, stream>>>(A, wsA);
    conv_b_kernel<<<2048, 256, 0, stream>>>(B, wsB);
    (void)hipFuncSetAttribute((const void*)gemm8_kernel,
                              hipFuncAttributeMaxDynamicSharedMemorySize, 131072);
    gemm8_kernel<<<768, 512, 131072, stream>>>(wsA, wsB, C);      // cols 0..24575
    gemm_rem_kernel<<<64, 256, 0, stream>>>(wsA, wsB, C);         // cols 24576..25087
  } else {
    gemm_fb_kernel<<<3136, 256, 0, stream>>>(A, B, C);
  }
}

// Round 4
// 3788.611 us; speedup vs baseline: 1.2003x; 1.2003x over previous
//
#include <hip/hip_runtime.h>
#include <hip/hip_bf16.h>
#include <stdint.h>

#define M_DIM 2048
#define N_DIM 25000
#define K_DIM 32000
#define N_PAD 25088            // 98 * 256
#define NT_K  500              // K_DIM / 64

typedef __attribute__((ext_vector_type(8))) short short8;
typedef __attribute__((ext_vector_type(4))) float f32x4;

typedef __attribute__((address_space(1))) const void* as1cv;
typedef __attribute__((address_space(3))) void* as3v;
#define GLDS16(g, l) __builtin_amdgcn_global_load_lds((as1cv)(g), (as3v)(l), 16, 0, 0)

// round-to-nearest-even fp32 -> bf16
__device__ inline unsigned short f2bf(float x) {
  union { float f; unsigned u; } c; c.f = x;
  unsigned u = c.u;
  return (unsigned short)((u + 0x7fffu + ((u >> 16) & 1u)) >> 16);
}

__device__ inline short8 pack8(float4 a, float4 b) {
  short8 s;
  s[0] = (short)f2bf(a.x); s[1] = (short)f2bf(a.y);
  s[2] = (short)f2bf(a.z); s[3] = (short)f2bf(a.w);
  s[4] = (short)f2bf(b.x); s[5] = (short)f2bf(b.y);
  s[6] = (short)f2bf(b.z); s[7] = (short)f2bf(b.w);
  return s;
}

// ---------------- convert kernels (fp32 -> bf16 in workspace) ----------------

__global__ __launch_bounds__(256) void conv_a_kernel(const float* __restrict__ in,
                                                     unsigned short* __restrict__ out) {
  const size_t n8 = (size_t)M_DIM * K_DIM / 8;
  const size_t stride = (size_t)gridDim.x * blockDim.x;
  for (size_t i = (size_t)blockIdx.x * blockDim.x + threadIdx.x; i < n8; i += stride) {
    const float4* p = (const float4*)(in + i * 8);
    float4 v0 = p[0], v1 = p[1];
    *(short8*)(out + i * 8) = pack8(v0, v1);
  }
}

__global__ __launch_bounds__(256) void conv_b_kernel(const float* __restrict__ in,
                                                     unsigned short* __restrict__ out) {
  const size_t n8 = (size_t)N_PAD * K_DIM / 8;
  const size_t stride = (size_t)gridDim.x * blockDim.x;
  const size_t k8 = K_DIM / 8;  // 4000
  for (size_t i = (size_t)blockIdx.x * blockDim.x + threadIdx.x; i < n8; i += stride) {
    const size_t row = i / k8;
    short8 s = {0, 0, 0, 0, 0, 0, 0, 0};
    if (row < N_DIM) {
      const float4* p = (const float4*)(in + i * 8);
      float4 v0 = p[0], v1 = p[1];
      s = pack8(v0, v1);
    }
    *(short8*)(out + i * 8) = s;
  }
}

// zero the C tail strip (rows 0..2047, cols 24576..24999) for atomic accumulation
__global__ __launch_bounds__(256) void zero_tail_kernel(float* __restrict__ C) {
  const int ntail = 25000 - 24576;  // 424
  const size_t n = (size_t)M_DIM * ntail;
  const size_t stride = (size_t)gridDim.x * blockDim.x;
  for (size_t i = (size_t)blockIdx.x * blockDim.x + threadIdx.x; i < n; i += stride) {
    const size_t r = i / ntail, c = i % ntail;
    C[r * N_DIM + 24576 + c] = 0.f;
  }
}

// ---------------- 256x256 8-phase GEMM, deep prefetch (vmcnt(6)) ----------------
// LDS per buffer: A 256x64 bf16 as 32 subtiles (16 rows x 32 cols, 1024 B), then B.
// Swizzle within subtile: 16B-chunk c' = c ^ ((row>>1)&3), applied to the
// pre-swizzled GLOBAL source on stage and to the ds_read address (rule 21).
//
// Stage schedule (steady state, iteration = tiles t (buf0), t+1 (buf1)):
//   P1: A(t+1)h1 | P3: B(t+2)h0 | P4: B(t+2)h1 + A(t+2)h0 | P5: A(t+2)h1
//   P7: B(t+3)h0 | P8: B(t+3)h1 + A(t+3)h0
// vmcnt(6) at end-P4 / end-P8 only; every waited half has 3-5 phases of flight.

#define BARR  __builtin_amdgcn_s_barrier()
#define LGKM0 do { asm volatile("s_waitcnt lgkmcnt(0)" ::: "memory"); \
                   __builtin_amdgcn_sched_barrier(0); } while (0)
#define LGKM8 asm volatile("s_waitcnt lgkmcnt(8)" ::: "memory")
#define VMC6  asm volatile("s_waitcnt vmcnt(6)" ::: "memory")
#define VMC0  asm volatile("s_waitcnt vmcnt(0)" ::: "memory")
#define PRIO1 __builtin_amdgcn_s_setprio(1)
#define PRIO0 __builtin_amdgcn_s_setprio(0)

#define READ_AF(P, MH) { _Pragma("unroll") for (int m2_ = 0; m2_ < 4; ++m2_) { \
  _Pragma("unroll") for (int kk_ = 0; kk_ < 2; ++kk_) \
    af[m2_][kk_] = *(const short8*)(rdA##P + (((MH) * 4 + m2_) * 2 + kk_) * 512); } }

#define READ_BF(P, NH) { _Pragma("unroll") for (int n2_ = 0; n2_ < 2; ++n2_) { \
  _Pragma("unroll") for (int kk_ = 0; kk_ < 2; ++kk_) \
    bf[NH][n2_][kk_] = *(const short8*)(rdB##P + (((NH) * 2 + n2_) * 2 + kk_) * 512); } }

#define MFMA_Q(MH, NH) { _Pragma("unroll") for (int kk_ = 0; kk_ < 2; ++kk_) { \
  _Pragma("unroll") for (int m2_ = 0; m2_ < 4; ++m2_) { \
  _Pragma("unroll") for (int n2_ = 0; n2_ < 2; ++n2_) \
    acc[(MH)*4+m2_][(NH)*2+n2_] = __builtin_amdgcn_mfma_f32_16x16x32_bf16( \
        af[m2_][kk_], bf[NH][n2_][kk_], acc[(MH)*4+m2_][(NH)*2+n2_], 0, 0, 0); } } }

#define STAGE_A(P, KT, H) do { \
  const unsigned short* s_ = agp + (size_t)(H) * (128 * (size_t)K_DIM) + (size_t)(KT) * 64; \
  GLDS16(s_,      stA##P + (H) * 8192); \
  GLDS16(s_ + 32, stA##P + (H) * 8192 + 512); } while (0)

#define STAGE_B(P, KT, H) do { \
  const unsigned short* s_ = bgp + (size_t)(H) * (128 * (size_t)K_DIM) + (size_t)(KT) * 64; \
  GLDS16(s_,      stB##P + (H) * 8192); \
  GLDS16(s_ + 32, stB##P + (H) * 8192 + 512); } while (0)

__global__ __launch_bounds__(512, 2)
void gemm8_kernel(const unsigned short* __restrict__ A, const unsigned short* __restrict__ B,
                  float* __restrict__ C) {
  extern __shared__ __align__(16) unsigned short lds[];  // 131072 B
  unsigned short* const LA0 = lds;
  unsigned short* const LB0 = lds + 16384;
  unsigned short* const LA1 = lds + 32768;
  unsigned short* const LB1 = lds + 49152;

  const int bid = blockIdx.x;
  const int wg = (bid & 7) * 96 + (bid >> 3);   // bijective XCD chunking (768 % 8 == 0)
  const int tm = wg & 7;                        // M tile 0..7 (fastest: shares B panel)
  const int tn = wg >> 3;                       // N tile 0..95 (cols 0..24575)
  const int tid = threadIdx.x;
  const int lane = tid & 63;
  const int w = tid >> 6;        // wave 0..7
  const int wm = w >> 2;         // 2 waves in M (128 rows each)
  const int wn = w & 3;          // 4 waves in N (64 cols each)

  const int laneoff = (lane & 15) * 32 + (((lane >> 4) ^ ((lane >> 1) & 3)) << 3);
  const unsigned short* const rdA0 = LA0 + wm * (16 * 512) + laneoff;
  const unsigned short* const rdA1 = LA1 + wm * (16 * 512) + laneoff;
  const int bsub = (wn >> 1) * 16 + (wn & 1) * 8;
  const unsigned short* const rdB0 = LB0 + bsub * 512 + laneoff;
  const unsigned short* const rdB1 = LB1 + bsub * 512 + laneoff;

  const int srow = w * 16 + (lane >> 2);
  const int schunk = ((lane & 3) ^ ((lane >> 3) & 3)) * 8;
  const unsigned short* const agp = A + (size_t)(tm * 256 + srow) * K_DIM + schunk;
  const unsigned short* const bgp = B + (size_t)(tn * 256 + srow) * K_DIM + schunk;
  unsigned short* const stA0 = LA0 + w * 1024;
  unsigned short* const stA1 = LA1 + w * 1024;
  unsigned short* const stB0 = LB0 + w * 1024;
  unsigned short* const stB1 = LB1 + w * 1024;

  f32x4 acc[8][4];
  const f32x4 z4 = {0.f, 0.f, 0.f, 0.f};
  #pragma unroll
  for (int i = 0; i < 8; ++i)
    #pragma unroll
    for (int j = 0; j < 4; ++j) acc[i][j] = z4;

  short8 af[4][2];      // current mh: 4 m-frags x 2 k-slices
  short8 bf[2][2][2];   // [nh][n'][kk]

  // ---- prologue: tile0 (4 halves) + tile1 {Bh0, Bh1, Ah0}; drain tile0 ----
  STAGE_B(0, 0, 0); STAGE_B(0, 0, 1);
  STAGE_A(0, 0, 0); STAGE_A(0, 0, 1);
  STAGE_B(1, 1, 0); STAGE_B(1, 1, 1); STAGE_A(1, 1, 0);
  VMC6; BARR;

  // ---- main loop: tiles (t, t+1), t = 0,2,...,496 ----
  #pragma unroll 1
  for (int it = 0; it < 249; ++it) {
    const int t = 2 * it;
    // P1: reads for Q(0,0); stage A(t+1)h1 -> buf1
    READ_AF(0, 0); READ_BF(0, 0); STAGE_A(1, t + 1, 1);
    LGKM8; BARR; LGKM0; PRIO1; MFMA_Q(0, 0); PRIO0; BARR;
    // P2
    READ_BF(0, 1);
    BARR; LGKM0; PRIO1; MFMA_Q(0, 1); PRIO0; BARR;
    // P3: stage B(t+2)h0 -> buf0  [buf0.B free after P2]
    READ_AF(0, 1); STAGE_B(0, t + 2, 0);
    BARR; LGKM0; PRIO1; MFMA_Q(1, 1); PRIO0; BARR;
    // P4: stage B(t+2)h1 + A(t+2)h0 -> buf0  [buf0.A free after P3]; wait tile t+1
    STAGE_B(0, t + 2, 1); STAGE_A(0, t + 2, 0);
    BARR; PRIO1; MFMA_Q(1, 0); PRIO0; VMC6; BARR;
    // P5: stage A(t+2)h1 -> buf0
    READ_AF(1, 0); READ_BF(1, 0); STAGE_A(0, t + 2, 1);
    LGKM8; BARR; LGKM0; PRIO1; MFMA_Q(0, 0); PRIO0; BARR;
    // P6
    READ_BF(1, 1);
    BARR; LGKM0; PRIO1; MFMA_Q(0, 1); PRIO0; BARR;
    // P7: stage B(t+3)h0 -> buf1  [buf1.B free after P6]
    READ_AF(1, 1); STAGE_B(1, t + 3, 0);
    BARR; LGKM0; PRIO1; MFMA_Q(1, 1); PRIO0; BARR;
    // P8: stage B(t+3)h1 + A(t+3)h0 -> buf1  [buf1.A free after P7]; wait tile t+2
    STAGE_B(1, t + 3, 1); STAGE_A(1, t + 3, 0);
    BARR; PRIO1; MFMA_Q(1, 0); PRIO0; VMC6; BARR;
  }

  // ---- tail: tile 498 (buf0; stage A(499)h1), then tile 499 (buf1) ----
  READ_AF(0, 0); READ_BF(0, 0); STAGE_A(1, 499, 1);
  LGKM8; BARR; LGKM0; PRIO1; MFMA_Q(0, 0); PRIO0; BARR;
  READ_BF(0, 1);
  BARR; LGKM0; PRIO1; MFMA_Q(0, 1); PRIO0; BARR;
  READ_AF(0, 1);
  BARR; LGKM0; PRIO1; MFMA_Q(1, 1); PRIO0; BARR;
  BARR; PRIO1; MFMA_Q(1, 0); PRIO0; VMC0; BARR;
  READ_AF(1, 0); READ_BF(1, 0);
  LGKM8; BARR; LGKM0; PRIO1; MFMA_Q(0, 0); PRIO0; BARR;
  READ_BF(1, 1);
  BARR; LGKM0; PRIO1; MFMA_Q(0, 1); PRIO0; BARR;
  READ_AF(1, 1);
  BARR; LGKM0; PRIO1; MFMA_Q(1, 1); PRIO0; BARR;
  PRIO1; MFMA_Q(1, 0); PRIO0;

  // ---- epilogue: C/D layout col=lane&15, row=(lane>>4)*4+j [m89-verified] ----
  const int crow0 = tm * 256 + wm * 128 + (lane >> 4) * 4;
  const int ccol0 = tn * 256 + wn * 64 + (lane & 15);
  #pragma unroll
  for (int m = 0; m < 8; ++m) {
    #pragma unroll
    for (int n = 0; n < 4; ++n) {
      const int col = ccol0 + n * 16;
      float* cp = C + (size_t)(crow0 + m * 16) * N_DIM + col;
      #pragma unroll
      for (int j = 0; j < 4; ++j)
        cp[(size_t)j * N_DIM] = acc[m][n][j];
    }
  }
}

// ---------------- K-split tail: cols 24576..25087, 64 tiles x 8 K-chunks ----------------
// 512 blocks (2 co-resident/CU for latency overlap), each a 128^2 tile over a
// 62-63-BK-step K chunk; partials combined via native fp32 atomic add into the
// zeroed C tail strip. Breaks the 500-step serial K chain (r3's 820 us rem).

__device__ inline void mfma_tile_fb(const unsigned short* As, const unsigned short* Bs,
                                    f32x4 acc[4][4], int lane, int wr, int wc) {
  const int ar = lane & 15;
  const int ko = (lane >> 4) * 8;
  #pragma unroll
  for (int kk = 0; kk < 2; ++kk) {
    short8 a2[4], b2[4];
    #pragma unroll
    for (int m = 0; m < 4; ++m)
      a2[m] = *(const short8*)&As[(wr * 64 + m * 16 + ar) * 64 + kk * 32 + ko];
    #pragma unroll
    for (int n = 0; n < 4; ++n)
      b2[n] = *(const short8*)&Bs[(wc * 64 + n * 16 + ar) * 64 + kk * 32 + ko];
    #pragma unroll
    for (int m = 0; m < 4; ++m)
      #pragma unroll
      for (int n = 0; n < 4; ++n)
        acc[m][n] = __builtin_amdgcn_mfma_f32_16x16x32_bf16(a2[m], b2[n], acc[m][n], 0, 0, 0);
  }
}

__global__ __launch_bounds__(256, 2)
void gemm_rem_split_kernel(const unsigned short* __restrict__ A,
                           const unsigned short* __restrict__ B,
                           float* __restrict__ C) {
  __shared__ __align__(16) unsigned short As[128 * 64];
  __shared__ __align__(16) unsigned short Bs[128 * 64];
  const int bid = blockIdx.x;          // 512 blocks
  const int kc = bid & 7;              // K chunk 0..7
  const int tile = bid >> 3;           // 0..63
  const int tm = tile & 15;            // 16 M tiles of 128
  const int tn = 192 + (tile >> 4);    // cols 24576..25087 (B ws zero-padded)
  // chunks: kc<4 -> 63 steps at kc*63; kc>=4 -> 62 steps at 252+(kc-4)*62  (sum 500)
  const int nsteps = (kc < 4) ? 63 : 62;
  const int kt0 = (kc < 4) ? kc * 63 : 252 + (kc - 4) * 62;
  const int tid = threadIdx.x;
  const int lane = tid & 63;
  const int w = tid >> 6;
  const int wr = w >> 1;
  const int wc = w & 1;
  f32x4 acc[4][4];
  const f32x4 z4 = {0.f, 0.f, 0.f, 0.f};
  #pragma unroll
  for (int i = 0; i < 4; ++i)
    #pragma unroll
    for (int j = 0; j < 4; ++j) acc[i][j] = z4;
  const int lrow = lane >> 3;
  const int lc16 = lane & 7;
  const unsigned short* ag = A + (size_t)(tm * 128 + w * 32 + lrow) * K_DIM + (size_t)kt0 * 64 + lc16 * 8;
  const unsigned short* bg = B + (size_t)(tn * 128 + w * 32 + lrow) * K_DIM + (size_t)kt0 * 64 + lc16 * 8;
  for (int kt = 0; kt < nsteps; ++kt) {
    #pragma unroll
    for (int i = 0; i < 4; ++i) {
      GLDS16(ag + (size_t)(i * 8) * K_DIM, &As[(w * 32 + i * 8) * 64]);
      GLDS16(bg + (size_t)(i * 8) * K_DIM, &Bs[(w * 32 + i * 8) * 64]);
    }
    ag += 64; bg += 64;
    __syncthreads();
    mfma_tile_fb(As, Bs, acc, lane, wr, wc);
    __syncthreads();
  }
  const int crow0 = tm * 128 + wr * 64 + (lane >> 4) * 4;
  const int ccol0 = tn * 128 + wc * 64 + (lane & 15);
  #pragma unroll
  for (int m = 0; m < 4; ++m) {
    #pragma unroll
    for (int n = 0; n < 4; ++n) {
      const int col = ccol0 + n * 16;
      if (col < N_DIM) {
        float* cp = C + (size_t)(crow0 + m * 16) * N_DIM + col;
        #pragma unroll
        for (int j = 0; j < 4; ++j)
          unsafeAtomicAdd(cp + (size_t)j * N_DIM, acc[m][n][j]);  // global_atomic_add_f32
      }
    }
  }
}

// ---------------- fallback (r1-validated 128^2 reg-staged fp32 path) ----------------

__global__ __launch_bounds__(256, 2)
void gemm_fb_kernel(const float* __restrict__ A, const float* __restrict__ B,
                    float* __restrict__ C) {
  __shared__ __align__(16) unsigned short As[128 * 64];
  __shared__ __align__(16) unsigned short Bs[128 * 64];
  const int bid = blockIdx.x;
  const int wg = (bid & 7) * (3136 / 8) + (bid >> 3);
  const int tm = wg % 16;
  const int tn = wg / 16;
  const int tid = threadIdx.x;
  const int lane = tid & 63;
  const int w = tid >> 6;
  const int wr = w >> 1;
  const int wc = w & 1;
  f32x4 acc[4][4];
  const f32x4 z4 = {0.f, 0.f, 0.f, 0.f};
  #pragma unroll
  for (int i = 0; i < 4; ++i)
    #pragma unroll
    for (int j = 0; j < 4; ++j) acc[i][j] = z4;
  for (int kt = 0; kt < NT_K; ++kt) {
    const int k0 = kt * 64;
    #pragma unroll
    for (int r = 0; r < 4; ++r) {
      const int f0 = r * 512 + tid * 2;
      const int row = f0 >> 4;
      const int c4 = f0 & 15;
      const float* ga = A + (size_t)(tm * 128 + row) * K_DIM + k0 + c4 * 4;
      float4 v0 = *(const float4*)ga;
      float4 v1 = *(const float4*)(ga + 4);
      *(short8*)&As[row * 64 + c4 * 4] = pack8(v0, v1);
    }
    #pragma unroll
    for (int r = 0; r < 4; ++r) {
      const int f0 = r * 512 + tid * 2;
      const int row = f0 >> 4;
      const int c4 = f0 & 15;
      const int grow = tn * 128 + row;
      short8 s = {0, 0, 0, 0, 0, 0, 0, 0};
      if (grow < N_DIM) {
        const float* gb = B + (size_t)grow * K_DIM + k0 + c4 * 4;
        float4 v0 = *(const float4*)gb;
        float4 v1 = *(const float4*)(gb + 4);
        s = pack8(v0, v1);
      }
      *(short8*)&Bs[row * 64 + c4 * 4] = s;
    }
    __syncthreads();
    mfma_tile_fb(As, Bs, acc, lane, wr, wc);
    __syncthreads();
  }
  const int crow0 = tm * 128 + wr * 64 + (lane >> 4) * 4;
  const int ccol0 = tn * 128 + wc * 64 + (lane & 15);
  #pragma unroll
  for (int m = 0; m < 4; ++m) {
    #pragma unroll
    for (int n = 0; n < 4; ++n) {
      const int col = ccol0 + n * 16;
      if (col < N_DIM) {
        float* cp = C + (size_t)(crow0 + m * 16) * N_DIM + col;
        #pragma unroll
        for (int j = 0; j < 4; ++j)
          cp[(size_t)j * N_DIM] = acc[m][n][j];
      }
    }
  }
}

// ---------------- launch ----------------

extern "C" void kernel_launch(void* const* d_in, const int* in_sizes, int n_in,
                              void* d_out, int out_size, void* d_ws, size_t ws_size,
                              hipStream_t stream) {
  const float* A = (const float*)d_in[0];   // teacher_logits [2048][32000] fp32
  const float* B = (const float*)d_in[1];   // projection   [25000][32000] fp32
  float* C = (float*)d_out;                 // [2048][25000] fp32

  const size_t needA = (size_t)M_DIM * K_DIM * 2;
  const size_t needB = (size_t)N_PAD * K_DIM * 2;

  if (ws_size >= needA + needB) {
    unsigned short* wsA = (unsigned short*)d_ws;
    unsigned short* wsB = wsA + (size_t)M_DIM * K_DIM;
    conv_a_kernel<<<2048, 256, 0, stream>>>(A, wsA);
    conv_b_kernel<<<2048, 256, 0, stream>>>(B, wsB);
    zero_tail_kernel<<<512, 256, 0, stream>>>(C);
    (void)hipFuncSetAttribute((const void*)gemm8_kernel,
                              hipFuncAttributeMaxDynamicSharedMemorySize, 131072);
    gemm8_kernel<<<768, 512, 131072, stream>>>(wsA, wsB, C);          // cols 0..24575
    gemm_rem_split_kernel<<<512, 256, 0, stream>>>(wsA, wsB, C);      // cols 24576..24999
  } else {
    gemm_fb_kernel<<<3136, 256, 0, stream>>>(A, B, C);
  }
}